// Round 1
// baseline (1559.251 us; speedup 1.0000x reference)
//
#include <hip/hip_runtime.h>
#include <cmath>

// Problem constants (ResidualMultiheadAttention): E=1024, H=16, D=64, L=S=2048, N=2
#define L_DIM 2048
#define S_DIM 2048
#define NB    2
#define NHEAD 16
#define DH    64
#define ED    1024
#define BH    32            // NB*NHEAD batched heads
#define MROWS 4096          // L*NB token rows
#define QKV_STRIDE ((size_t)MROWS * ED)   // 4194304 floats per projection buffer
#define HSZ ((size_t)BH * S_DIM * DH)     // 4194304 elems per head-major buffer

typedef unsigned short u16;
typedef __attribute__((ext_vector_type(8))) short bfrag;   // 8 bf16 (4 VGPRs) MFMA A/B frag
typedef __attribute__((ext_vector_type(4))) float ffrag;   // 4 fp32 MFMA C/D frag

// float -> bf16 round-to-nearest-even (bit-exact, no API dependence)
__device__ __forceinline__ u16 f2bf(float x) {
    unsigned u = __float_as_uint(x);
    return (u16)((u + 0x7fffu + ((u >> 16) & 1u)) >> 16);
}
__device__ __forceinline__ float bf2f(u16 b) {
    return __uint_as_float(((unsigned)b) << 16);
}

// ---------------------------------------------------------------------------
// GEMM: X(4096x1024) @ W(1024x1024). 128x128 block, 8x8 microtile, BK=16.
// MODE 0: plain fp32 row-major store (output projection).
// MODE 1: head-major store; z==0 -> Q as bf16 hi/lo, z==1 -> K as bf16 hi/lo,
//         z==2 -> V as fp32 (consumed by the transpose kernel).
// ---------------------------------------------------------------------------
template<int MODE>
__global__ __launch_bounds__(256) void gemm_k(
    const float* __restrict__ X0, const float* __restrict__ X1, const float* __restrict__ X2,
    const float* __restrict__ W0, const float* __restrict__ W1, const float* __restrict__ W2,
    float* __restrict__ OutF,
    u16* __restrict__ qh, u16* __restrict__ ql,
    u16* __restrict__ kh, u16* __restrict__ kl)
{
    const int z = blockIdx.z;
    const float* X = (z == 0) ? X0 : (z == 1) ? X1 : X2;
    const float* W = (z == 0) ? W0 : (z == 1) ? W1 : W2;

    __shared__ float As[16][132];   // [k][m] transposed A tile
    __shared__ float Bs[16][132];   // [k][n] natural B tile

    const int tid = threadIdx.x;
    const int tx = tid & 15, ty = tid >> 4;
    const int m0 = blockIdx.y * 128;
    const int bn = blockIdx.x * 128;

    float acc[8][8];
    #pragma unroll
    for (int i = 0; i < 8; ++i)
        #pragma unroll
        for (int j = 0; j < 8; ++j) acc[i][j] = 0.f;

    for (int k0 = 0; k0 < ED; k0 += 16) {
        #pragma unroll
        for (int it = 0; it < 2; ++it) {
            const int idx = it * 256 + tid;        // 0..511
            const int jq  = idx & 3;               // k-quad
            const int m   = idx >> 2;              // 0..127
            const float4 a = *(const float4*)&X[(size_t)(m0 + m) * ED + k0 + 4 * jq];
            As[4*jq+0][m] = a.x; As[4*jq+1][m] = a.y;
            As[4*jq+2][m] = a.z; As[4*jq+3][m] = a.w;
        }
        #pragma unroll
        for (int it = 0; it < 2; ++it) {
            const int idx = it * 256 + tid;        // 0..511
            const int e4  = idx & 31;
            const int k   = idx >> 5;
            *(float4*)&Bs[k][4*e4] = *(const float4*)&W[(size_t)(k0 + k) * ED + bn + 4*e4];
        }
        __syncthreads();

        #pragma unroll 4
        for (int k = 0; k < 16; ++k) {
            const float4 a0 = *(const float4*)&As[k][4*ty];
            const float4 a1 = *(const float4*)&As[k][64 + 4*ty];
            const float4 b0 = *(const float4*)&Bs[k][4*tx];
            const float4 b1 = *(const float4*)&Bs[k][64 + 4*tx];
            const float av[8] = {a0.x,a0.y,a0.z,a0.w,a1.x,a1.y,a1.z,a1.w};
            const float bv[8] = {b0.x,b0.y,b0.z,b0.w,b1.x,b1.y,b1.z,b1.w};
            #pragma unroll
            for (int i = 0; i < 8; ++i)
                #pragma unroll
                for (int j = 0; j < 8; ++j)
                    acc[i][j] = fmaf(av[i], bv[j], acc[i][j]);
        }
        __syncthreads();
    }

    #pragma unroll
    for (int i = 0; i < 8; ++i) {
        const int r   = (i < 4) ? (4*ty + i) : (64 + 4*ty + (i - 4));
        const int row = m0 + r;
        #pragma unroll
        for (int jh = 0; jh < 2; ++jh) {
            const int e = bn + 64*jh + 4*tx;
            const float a0 = acc[i][4*jh+0], a1 = acc[i][4*jh+1];
            const float a2 = acc[i][4*jh+2], a3 = acc[i][4*jh+3];
            if (MODE == 0) {
                float4 v; v.x = a0; v.y = a1; v.z = a2; v.w = a3;
                *(float4*)&OutF[(size_t)row * ED + e] = v;
            } else {
                const int nn = row & 1, t = row >> 1;     // row = t*2 + n
                const int h = e >> 6, d = e & 63;         // e = h*64 + d
                const size_t off = ((size_t)((nn*NHEAD + h) * L_DIM + t)) * DH + d;
                if (z == 2) {
                    float4 v; v.x = a0; v.y = a1; v.z = a2; v.w = a3;
                    *(float4*)&OutF[off] = v;
                } else {
                    u16* __restrict__ ph = z ? kh : qh;
                    u16* __restrict__ pl = z ? kl : ql;
                    const u16 h0 = f2bf(a0), h1 = f2bf(a1), h2 = f2bf(a2), h3 = f2bf(a3);
                    ushort4 hv, lv;
                    hv.x = h0; hv.y = h1; hv.z = h2; hv.w = h3;
                    lv.x = f2bf(a0 - bf2f(h0)); lv.y = f2bf(a1 - bf2f(h1));
                    lv.z = f2bf(a2 - bf2f(h2)); lv.w = f2bf(a3 - bf2f(h3));
                    *(ushort4*)&ph[off] = hv;
                    *(ushort4*)&pl[off] = lv;
                }
            }
        }
    }
}

// ---------------------------------------------------------------------------
// V transpose+convert: vf [b][c(2048)][d(64)] fp32 -> vth/vtl [b][d][c] bf16 h/l
// ---------------------------------------------------------------------------
__global__ __launch_bounds__(256) void transv_k(
    const float* __restrict__ vf, u16* __restrict__ vth, u16* __restrict__ vtl)
{
    const int ct = blockIdx.x;   // 0..31 c-tile of 64
    const int b  = blockIdx.y;   // 0..31
    __shared__ float Vs[64][65];
    const int tid = threadIdx.x;

    #pragma unroll
    for (int it = 0; it < 4; ++it) {
        const int idx = it*256 + tid;       // 0..1023
        const int d4 = idx & 15, c = idx >> 4;
        const float4 v4 = *(const float4*)&vf[((size_t)b*S_DIM + ct*64 + c)*DH + 4*d4];
        Vs[c][4*d4+0] = v4.x; Vs[c][4*d4+1] = v4.y;
        Vs[c][4*d4+2] = v4.z; Vs[c][4*d4+3] = v4.w;
    }
    __syncthreads();

    #pragma unroll
    for (int it = 0; it < 2; ++it) {
        const int j = it*256 + tid;         // 0..511
        const int c8 = j & 7, d = j >> 3;
        unsigned hw[4], lw[4];
        #pragma unroll
        for (int q = 0; q < 8; q += 2) {
            const float x0 = Vs[8*c8 + q][d];
            const float x1 = Vs[8*c8 + q + 1][d];
            const u16 h0 = f2bf(x0), h1 = f2bf(x1);
            const u16 l0 = f2bf(x0 - bf2f(h0)), l1 = f2bf(x1 - bf2f(h1));
            hw[q>>1] = (unsigned)h0 | ((unsigned)h1 << 16);
            lw[q>>1] = (unsigned)l0 | ((unsigned)l1 << 16);
        }
        const size_t off = ((size_t)b*DH + d)*S_DIM + ct*64 + 8*c8;
        uint4 H;  H.x = hw[0];  H.y = hw[1];  H.z = hw[2];  H.w = hw[3];
        uint4 Lv; Lv.x = lw[0]; Lv.y = lw[1]; Lv.z = lw[2]; Lv.w = lw[3];
        *(uint4*)&vth[off] = H;
        *(uint4*)&vtl[off] = Lv;
    }
}

// ---------------------------------------------------------------------------
// Fused attention via MFMA (bf16 hi/lo x3 products == fp32-grade accuracy).
// Per block: head b, 64-row Q tile. 4 waves; wave w owns rows w*16..w*16+15.
// Q fragments in registers (no LDS). K and V^T staged in LDS as bf16 h/l.
// mfma_f32_16x16x32_bf16 layouts (learn_hip m89-verified):
//   A: row=lane&15, k=8*(lane>>4)+i   B: col=lane&15, k=8*(lane>>4)+i
//   C/D: col=lane&15, row=4*(lane>>4)+reg
// LDS row stride 88 u16 = 176 B = 11*16 B -> conflict-free b128 frag reads.
// ---------------------------------------------------------------------------
__global__ __launch_bounds__(256) void attn_kernel(
    const u16* __restrict__ qhp, const u16* __restrict__ qlp,
    const u16* __restrict__ khp, const u16* __restrict__ klp,
    const u16* __restrict__ vth, const u16* __restrict__ vtl,
    const float* __restrict__ prev,
    float* __restrict__ logits_out, float* __restrict__ attn_out)
{
    const int b  = blockIdx.x;   // 0..31  (b = n*16 + h)
    const int qt = blockIdx.y;   // 0..31
    const int tid  = threadIdx.x;
    const int w    = tid >> 6;   // wave 0..3
    const int lane = tid & 63;
    const int lr = lane & 15;    // 0..15
    const int lg = lane >> 4;    // 0..3

    __shared__ u16 Kh_s[64][88], Kl_s[64][88];   // [token c][d]
    __shared__ u16 Vh_s[64][88], Vl_s[64][88];   // [d][token c]  (V^T)
    __shared__ u16 Ph_s[64][88], Pl_s[64][88];   // [row][c]

    // Q fragments, held in registers across all 32 S-tiles
    const size_t qoff = ((size_t)b * S_DIM + (size_t)qt*64 + w*16 + lr) * DH + 8*lg;
    const bfrag qf_h0 = *(const bfrag*)&qhp[qoff];
    const bfrag qf_h1 = *(const bfrag*)&qhp[qoff + 32];
    const bfrag qf_l0 = *(const bfrag*)&qlp[qoff];
    const bfrag qf_l1 = *(const bfrag*)&qlp[qoff + 32];

    ffrag Oa[4];
    #pragma unroll
    for (int nf = 0; nf < 4; ++nf)
        #pragma unroll
        for (int j = 0; j < 4; ++j) Oa[nf][j] = 0.f;
    float m_i[4] = {-INFINITY, -INFINITY, -INFINITY, -INFINITY};
    float l_i[4] = {0.f, 0.f, 0.f, 0.f};

    for (int st = 0; st < 32; ++st) {
        // ---- stage K (h/l) and V^T (h/l): 16 B/lane chunks, fully coalesced ----
        #pragma unroll
        for (int it = 0; it < 2; ++it) {
            const int idx = it*256 + tid;           // 0..511
            const int q8 = idx & 7, rr = idx >> 3;  // chunk-in-row, row
            const size_t ko = ((size_t)b*S_DIM + st*64 + rr)*DH + 8*q8;
            *(uint4*)&Kh_s[rr][8*q8] = *(const uint4*)&khp[ko];
            *(uint4*)&Kl_s[rr][8*q8] = *(const uint4*)&klp[ko];
            const size_t vo = ((size_t)b*DH + rr)*S_DIM + st*64 + 8*q8;
            *(uint4*)&Vh_s[rr][8*q8] = *(const uint4*)&vth[vo];
            *(uint4*)&Vl_s[rr][8*q8] = *(const uint4*)&vtl[vo];
        }
        __syncthreads();

        // ---- S = Q K^T: 24 MFMA (2 k-steps x 4 col-frags x 3 hi/lo products) ----
        ffrag sa[4];
        #pragma unroll
        for (int nf = 0; nf < 4; ++nf)
            #pragma unroll
            for (int j = 0; j < 4; ++j) sa[nf][j] = 0.f;
        #pragma unroll
        for (int k0 = 0; k0 < 2; ++k0) {
            const bfrag aqh = k0 ? qf_h1 : qf_h0;
            const bfrag aql = k0 ? qf_l1 : qf_l0;
            #pragma unroll
            for (int nf = 0; nf < 4; ++nf) {
                const bfrag bh = *(const bfrag*)&Kh_s[16*nf + lr][k0*32 + 8*lg];
                const bfrag bl = *(const bfrag*)&Kl_s[16*nf + lr][k0*32 + 8*lg];
                sa[nf] = __builtin_amdgcn_mfma_f32_16x16x32_bf16(aqh, bh, sa[nf], 0, 0, 0);
                sa[nf] = __builtin_amdgcn_mfma_f32_16x16x32_bf16(aqh, bl, sa[nf], 0, 0, 0);
                sa[nf] = __builtin_amdgcn_mfma_f32_16x16x32_bf16(aql, bh, sa[nf], 0, 0, 0);
            }
        }

        // ---- scale + residual -> logits; online softmax; stash P (bf16 h/l) ----
        #pragma unroll
        for (int r = 0; r < 4; ++r) {
            const int rw   = 4*lg + r;              // row within wave tile
            const int trow = qt*64 + w*16 + rw;
            const size_t off = ((size_t)b * L_DIM + trow) * S_DIM + st*64 + lr;
            const float v0 = fmaf(sa[0][r], 0.125f, prev[off]);
            const float v1 = fmaf(sa[1][r], 0.125f, prev[off + 16]);
            const float v2 = fmaf(sa[2][r], 0.125f, prev[off + 32]);
            const float v3 = fmaf(sa[3][r], 0.125f, prev[off + 48]);
            logits_out[off]      = v0;
            logits_out[off + 16] = v1;
            logits_out[off + 32] = v2;
            logits_out[off + 48] = v3;

            float mx = fmaxf(fmaxf(v0, v1), fmaxf(v2, v3));
            #pragma unroll
            for (int msk = 1; msk < 16; msk <<= 1)
                mx = fmaxf(mx, __shfl_xor(mx, msk, 64));
            const float mnew  = fmaxf(m_i[r], mx);
            const float alpha = __expf(m_i[r] - mnew);
            m_i[r] = mnew;
            const float p0 = __expf(v0 - mnew), p1 = __expf(v1 - mnew);
            const float p2 = __expf(v2 - mnew), p3 = __expf(v3 - mnew);
            float ps = (p0 + p1) + (p2 + p3);
            #pragma unroll
            for (int msk = 1; msk < 16; msk <<= 1)
                ps += __shfl_xor(ps, msk, 64);
            l_i[r] = l_i[r] * alpha + ps;
            #pragma unroll
            for (int nf = 0; nf < 4; ++nf) Oa[nf][r] *= alpha;

            const int prow = w*16 + rw;
            const u16 h0 = f2bf(p0), h1 = f2bf(p1), h2 = f2bf(p2), h3 = f2bf(p3);
            Ph_s[prow][lr]      = h0;  Pl_s[prow][lr]      = f2bf(p0 - bf2f(h0));
            Ph_s[prow][lr + 16] = h1;  Pl_s[prow][lr + 16] = f2bf(p1 - bf2f(h1));
            Ph_s[prow][lr + 32] = h2;  Pl_s[prow][lr + 32] = f2bf(p2 - bf2f(h2));
            Ph_s[prow][lr + 48] = h3;  Pl_s[prow][lr + 48] = f2bf(p3 - bf2f(h3));
        }
        __syncthreads();

        // ---- O += P V: 24 MFMA ----
        #pragma unroll
        for (int k0 = 0; k0 < 2; ++k0) {
            const bfrag pah = *(const bfrag*)&Ph_s[w*16 + lr][k0*32 + 8*lg];
            const bfrag pal = *(const bfrag*)&Pl_s[w*16 + lr][k0*32 + 8*lg];
            #pragma unroll
            for (int nf = 0; nf < 4; ++nf) {
                const bfrag bvh = *(const bfrag*)&Vh_s[16*nf + lr][k0*32 + 8*lg];
                const bfrag bvl = *(const bfrag*)&Vl_s[16*nf + lr][k0*32 + 8*lg];
                Oa[nf] = __builtin_amdgcn_mfma_f32_16x16x32_bf16(pah, bvh, Oa[nf], 0, 0, 0);
                Oa[nf] = __builtin_amdgcn_mfma_f32_16x16x32_bf16(pah, bvl, Oa[nf], 0, 0, 0);
                Oa[nf] = __builtin_amdgcn_mfma_f32_16x16x32_bf16(pal, bvh, Oa[nf], 0, 0, 0);
            }
        }
        __syncthreads();
    }

    // ---- epilogue: normalize, write attn_out rows (t*2+n), cols h*64+d ----
    const int nn = b >> 4, hh = b & 15;
    #pragma unroll
    for (int r = 0; r < 4; ++r) {
        const int trow = qt*64 + w*16 + 4*lg + r;
        const float inv = 1.0f / l_i[r];
        #pragma unroll
        for (int nf = 0; nf < 4; ++nf)
            attn_out[((size_t)(trow*NB + nn))*ED + hh*DH + 16*nf + lr] = Oa[nf][r] * inv;
    }
}

// ---------------------------------------------------------------------------
extern "C" void kernel_launch(void* const* d_in, const int* in_sizes, int n_in,
                              void* d_out, int out_size, void* d_ws, size_t ws_size,
                              hipStream_t stream) {
    const float* query = (const float*)d_in[0];
    const float* key   = (const float*)d_in[1];
    const float* value = (const float*)d_in[2];
    const float* prev  = (const float*)d_in[3];
    // d_in[4] key_padding_mask, d_in[5] attn_mask: all-false in this problem -> no-op
    const float* Wq = (const float*)d_in[6];
    const float* Wk = (const float*)d_in[7];
    const float* Wv = (const float*)d_in[8];
    const float* Wo = (const float*)d_in[9];

    float* out    = (float*)d_out;                    // (L, N, E) = 4194304 floats
    float* logits = out + QKV_STRIDE;                 // (32, 2048, 2048) follows

    // workspace: 6 bf16 head-major buffers + 1 fp32 buffer = 67,108,864 B
    // (byte-identical footprint to previous kernel's 4 fp32 buffers)
    u16* qh  = (u16*)d_ws;
    u16* ql  = qh  + HSZ;
    u16* kh  = ql  + HSZ;
    u16* kl  = kh  + HSZ;
    u16* vth = kl  + HSZ;
    u16* vtl = vth + HSZ;
    float* vf     = (float*)(vtl + HSZ);   // V fp32 head-major (transpose input)
    float* attn_o = vf;                    // alias: vf dead after transv_k

    dim3 blk(256);
    // QKV projections: Q,K -> bf16 hi/lo head-major; V -> fp32 head-major
    gemm_k<1><<<dim3(8, 32, 3), blk, 0, stream>>>(
        query, key, value, Wq, Wk, Wv, vf, qh, ql, kh, kl);
    // V -> V^T bf16 hi/lo
    transv_k<<<dim3(32, 32), blk, 0, stream>>>(vf, vth, vtl);
    // fused residual attention (MFMA): writes logits output + attn_o
    attn_kernel<<<dim3(32, 32), blk, 0, stream>>>(
        qh, ql, kh, kl, vth, vtl, prev, logits, attn_o);
    // output projection -> d_out
    gemm_k<0><<<dim3(8, 32, 1), blk, 0, stream>>>(
        attn_o, attn_o, attn_o, Wo, Wo, Wo, out,
        (u16*)nullptr, (u16*)nullptr, (u16*)nullptr, (u16*)nullptr);
}